// Round 3
// baseline (573.805 us; speedup 1.0000x reference)
//
#include <hip/hip_runtime.h>

#define NN 512
#define CCH 128
#define MM (NN*NN)   // 262144

using f32x4  = __attribute__((ext_vector_type(4))) float;
using f32x2  = __attribute__((ext_vector_type(2))) float;
using bf16x8 = __attribute__((ext_vector_type(8))) short;
using u16x4  = __attribute__((ext_vector_type(4))) unsigned short;
typedef unsigned short u16;

__device__ __forceinline__ u16 f2bf(float f) {
    unsigned u = __builtin_bit_cast(unsigned, f);
    u += 0x7FFF + ((u >> 16) & 1);
    return (u16)(u >> 16);
}
__device__ __forceinline__ float bf2f(u16 h) {
    unsigned u = ((unsigned)h) << 16;
    return __builtin_bit_cast(float, u);
}
__device__ __forceinline__ float sigm(float x) { return 1.0f / (1.0f + __expf(-x)); }

__device__ __forceinline__ void gl_lds16(const void* g, void* l) {
    __builtin_amdgcn_global_load_lds(
        (const __attribute__((address_space(1))) void*)g,
        (__attribute__((address_space(3))) void*)l, 16, 0, 0);
}

// ---------------- k_prep: fold LN gamma/beta into bf16 weights + biases ----
__global__ __launch_bounds__(256) void k_prep(
    const float* __restrict__ w0, const float* __restrict__ w1,
    const float* __restrict__ w2, const float* __restrict__ w3,
    const float* __restrict__ w4, const float* __restrict__ w5,
    const float* __restrict__ b0, const float* __restrict__ b1,
    const float* __restrict__ b2, const float* __restrict__ b3,
    const float* __restrict__ b4, const float* __restrict__ b5,
    const float* __restrict__ gin, const float* __restrict__ bin,
    const float* __restrict__ gout, const float* __restrict__ bout,
    u16* __restrict__ wbf, float* __restrict__ bias2) {
    int mat = blockIdx.x;
    const float* W = mat==0?w0:mat==1?w1:mat==2?w2:mat==3?w3:mat==4?w4:w5;
    const float* B = mat==0?b0:mat==1?b1:mat==2?b2:mat==3?b3:mat==4?b4:b5;
    const float* G = (mat==5)? gout : gin;
    const float* Bt= (mat==5)? bout : bin;
    __shared__ float gs[CCH], bs[CCH];
    int tid = threadIdx.x;
    if (tid < CCH) { gs[tid] = G[tid]; bs[tid] = Bt[tid]; }
    __syncthreads();
    int o = tid >> 1, c0 = (tid & 1) * 64;
    const float* src = W + o * CCH + c0;
    u16* dst = wbf + mat * 16384 + o * CCH + c0;
    float dot = 0.f;
    #pragma unroll
    for (int q = 0; q < 16; ++q) {
        f32x4 v = *(const f32x4*)(src + q * 4);
        int c = c0 + q * 4;
        dot += bs[c]*v.x + bs[c+1]*v.y + bs[c+2]*v.z + bs[c+3]*v.w;
        u16x4 p;
        p.x = f2bf(v.x * gs[c]);     p.y = f2bf(v.y * gs[c+1]);
        p.z = f2bf(v.z * gs[c+2]);   p.w = f2bf(v.w * gs[c+3]);
        *(u16x4*)(dst + q * 4) = p;
    }
    dot += __shfl_xor(dot, 1);
    if ((tid & 1) == 0) bias2[mat * CCH + o] = B[o] + dot;
}

// ---------------- k_projLN: LN(z) + 5 projections (64 rows/block) ----------
// aT/bT layout: plane c, byte = m*2, but within each 128B k-group the 16B
// chunk index is XORed with (i&7), i = m/512 (matches k_tri's swizzled read).
__global__ __launch_bounds__(256, 4) void k_projLN(
    const float* __restrict__ z, const float* __restrict__ mask,
    const u16* __restrict__ wbf, const float* __restrict__ bias2,
    u16* __restrict__ aT, u16* __restrict__ bT, u16* gateB) {
    __shared__ __align__(16) u16 tb[8192];   // 16KB: [64m][128c] then [128c][64m]
    int tid = threadIdx.x, w = tid >> 6, lane = tid & 63;
    int r = lane & 15, kq = lane >> 4;
    long m0 = (long)blockIdx.x * 64;
    int i7 = (int)((m0 >> 9) & 7);

    // --- LN stage: 4 threads per row ---
    {
        int row = tid >> 2, p = tid & 3, c0 = p * 32;
        const float* zr = z + (m0 + row) * CCH + c0;
        f32x4 va[8];
        float s = 0.f, s2 = 0.f;
        #pragma unroll
        for (int q = 0; q < 8; ++q) {
            va[q] = *(const f32x4*)(zr + q * 4);
            s  += va[q].x + va[q].y + va[q].z + va[q].w;
            s2 += va[q].x*va[q].x + va[q].y*va[q].y + va[q].z*va[q].z + va[q].w*va[q].w;
        }
        s += __shfl_xor(s, 1); s += __shfl_xor(s, 2);
        s2 += __shfl_xor(s2, 1); s2 += __shfl_xor(s2, 2);
        float mu = s * (1.0f / CCH);
        float var = s2 * (1.0f / CCH) - mu * mu;
        float rs = rsqrtf(var + 1e-5f);
        int sw = (row & 15) << 4;
        #pragma unroll
        for (int q2 = 0; q2 < 4; ++q2) {
            f32x4 v0 = va[q2*2], v1 = va[q2*2+1];
            u16x4 pa, pb;
            pa.x = f2bf((v0.x-mu)*rs); pa.y = f2bf((v0.y-mu)*rs);
            pa.z = f2bf((v0.z-mu)*rs); pa.w = f2bf((v0.w-mu)*rs);
            pb.x = f2bf((v1.x-mu)*rs); pb.y = f2bf((v1.y-mu)*rs);
            pb.z = f2bf((v1.z-mu)*rs); pb.w = f2bf((v1.w-mu)*rs);
            char* p8 = (char*)tb + row * 256 + ((c0 * 2 + q2 * 16) ^ sw);
            *(u16x4*)p8 = pa;
            *(u16x4*)(p8 + 8) = pb;
        }
    }
    __syncthreads();

    // --- A-fragments: wave w owns rows w*16..w*16+15 ---
    bf16x8 av[4];
    {
        int row = w * 16 + r, sw = (row & 15) << 4;
        #pragma unroll
        for (int kb = 0; kb < 4; ++kb)
            av[kb] = *(const bf16x8*)((const char*)tb + row * 256 + ((kb * 64 + kq * 16) ^ sw));
    }
    f32x4 mkv = *(const f32x4*)(mask + m0 + w * 16 + kq * 4);

    // --- phases 0,1: gated pair-GEMMs -> aT / bT ---
    #pragma unroll 1
    for (int ph = 0; ph < 2; ++ph) {
        const u16* W1 = wbf + (ph * 2 + 0) * 16384;
        const u16* W2 = wbf + (ph * 2 + 1) * 16384;
        f32x4 a1[8], a2[8];
        #pragma unroll
        for (int nt = 0; nt < 8; ++nt) { a1[nt] = {0,0,0,0}; a2[nt] = {0,0,0,0}; }
        #pragma unroll
        for (int nt = 0; nt < 8; ++nt) {
            #pragma unroll
            for (int kb = 0; kb < 4; ++kb) {
                int off = (nt * 16 + r) * CCH + kb * 32 + kq * 8;
                bf16x8 bw1 = *(const bf16x8*)(W1 + off);
                bf16x8 bw2 = *(const bf16x8*)(W2 + off);
                a1[nt] = __builtin_amdgcn_mfma_f32_16x16x32_bf16(av[kb], bw1, a1[nt], 0, 0, 0);
                a2[nt] = __builtin_amdgcn_mfma_f32_16x16x32_bf16(av[kb], bw2, a2[nt], 0, 0, 0);
            }
        }
        __syncthreads();   // tb readers (av / prev readout) done
        const float* B1 = bias2 + (ph * 2 + 0) * CCH;
        const float* B2 = bias2 + (ph * 2 + 1) * CCH;
        int ml0 = w * 16 + kq * 4;
        #pragma unroll
        for (int nt = 0; nt < 8; ++nt) {
            int cc = nt * 16 + r;
            float b1v = B1[cc], b2v = B2[cc];
            u16x4 p;
            #pragma unroll
            for (int j = 0; j < 4; ++j) {
                float val = mkv[j] * sigm(a1[nt][j] + b1v) * (a2[nt][j] + b2v);
                p[j] = f2bf(val);
            }
            *(u16x4*)((char*)tb + cc * 128 + ((ml0 * 2) ^ ((cc & 7) << 4))) = p;
        }
        __syncthreads();
        u16* dst = ph ? bT : aT;
        int c = tid >> 1, half = tid & 1, swc = (c & 7) << 4;
        const char* src = (const char*)tb + c * 128;
        char* gdst = (char*)(dst + (long)c * MM) + m0 * 2;
        #pragma unroll
        for (int qq = 0; qq < 4; ++qq) {
            bf16x8 vv = *(const bf16x8*)(src + ((half * 64 + qq * 16) ^ swc));
            *(bf16x8*)(gdst + (((half * 4 + qq) ^ i7) << 4)) = vv;
        }
    }

    // --- gate phase: sigm(zn @ w_g'^T + b2_g) -> d_out row heads (bf16) ---
    {
        const u16* Wg = wbf + 4 * 16384;
        f32x4 g[8];
        #pragma unroll
        for (int nt = 0; nt < 8; ++nt) g[nt] = {0,0,0,0};
        #pragma unroll
        for (int nt = 0; nt < 8; ++nt) {
            #pragma unroll
            for (int kb = 0; kb < 4; ++kb) {
                bf16x8 bw = *(const bf16x8*)(Wg + (nt * 16 + r) * CCH + kb * 32 + kq * 8);
                g[nt] = __builtin_amdgcn_mfma_f32_16x16x32_bf16(av[kb], bw, g[nt], 0, 0, 0);
            }
        }
        #pragma unroll
        for (int nt = 0; nt < 8; ++nt) {
            int cc = nt * 16 + r;
            float bgv = bias2[4 * CCH + cc];
            #pragma unroll
            for (int j = 0; j < 4; ++j) {
                long m = m0 + w * 16 + kq * 4 + j;
                gateB[m * 256 + cc] = f2bf(sigm(g[nt][j] + bgv));
            }
        }
    }
}

// ---------------- k_tri: per-channel triangle GEMM, BK=64 ------------------
// xT[c][i*512+j] = sum_k aT[c][i][k] * bT[c][j][k]  (aT/bT chunk-swizzled)
__global__ __launch_bounds__(256, 4) void k_tri(const u16* __restrict__ aT,
                                                const u16* __restrict__ bT,
                                                u16* __restrict__ xT) {
    __shared__ __align__(16) u16 At[128 * 64];  // 16KB: [128 rows][128B]
    __shared__ __align__(16) u16 Bt[128 * 64];
    int tid = threadIdx.x;
    int w = tid >> 6, lane = tid & 63;
    int r = lane & 15, kq = lane >> 4;

    // XCD-locality remap: 16 tiles of one c stay on one XCD
    int L = blockIdx.x;
    int xcd = L & 7, idx = L >> 3;
    int c    = xcd + 8 * (idx >> 4);
    int tile = idx & 15;
    int ti = tile >> 2, tj = tile & 3;

    const char* abase = (const char*)(aT + (long)c * MM) + (long)(ti * 128) * 1024;
    const char* bbase = (const char*)(bT + (long)c * MM) + (long)(tj * 128) * 1024;
    int wm = w >> 1, wn = w & 1;

    f32x4 acc[4][4];
    #pragma unroll
    for (int a = 0; a < 4; ++a)
        #pragma unroll
        for (int bq = 0; bq < 4; ++bq) acc[a][bq] = {0.f,0.f,0.f,0.f};

    for (int ks = 0; ks < 8; ++ks) {
        const char* asrc = abase + ks * 128;
        const char* bsrc = bbase + ks * 128;
        #pragma unroll
        for (int it = 0; it < 4; ++it) {
            int u = it * 256 + tid;
            long goff = (long)(u >> 3) * 1024 + (u & 7) * 16;
            gl_lds16(asrc + goff, (char*)At + it * 4096 + w * 1024);
            gl_lds16(bsrc + goff, (char*)Bt + it * 4096 + w * 1024);
        }
        __syncthreads();

        #pragma unroll
        for (int kh = 0; kh < 2; ++kh) {
            bf16x8 af[4];
            #pragma unroll
            for (int mt = 0; mt < 4; ++mt) {
                int rowa = wm * 64 + mt * 16 + r;
                af[mt] = *(const bf16x8*)((const char*)At + rowa * 128 +
                                          (((kh * 4 + kq) ^ (r & 7)) << 4));
            }
            #pragma unroll
            for (int nt = 0; nt < 4; ++nt) {
                int rowb = wn * 64 + nt * 16 + r;
                bf16x8 bf = *(const bf16x8*)((const char*)Bt + rowb * 128 +
                                             (((kh * 4 + kq) ^ (r & 7)) << 4));
                #pragma unroll
                for (int mt = 0; mt < 4; ++mt)
                    acc[mt][nt] = __builtin_amdgcn_mfma_f32_16x16x32_bf16(af[mt], bf, acc[mt][nt], 0, 0, 0);
            }
        }
        __syncthreads();
    }

    u16* xbase = xT + (long)c * MM;
    int gi0 = ti * 128 + wm * 64;
    int gj0 = tj * 128 + wn * 64 + r;
    #pragma unroll
    for (int mt = 0; mt < 4; ++mt)
        #pragma unroll
        for (int nt = 0; nt < 4; ++nt)
            #pragma unroll
            for (int j = 0; j < 4; ++j) {
                long gi = gi0 + mt * 16 + kq * 4 + j;
                xbase[gi * NN + gj0 + nt * 16] = f2bf(acc[mt][nt][j]);
            }
}

// ---------------- k_out: LN(x) @ w_z''^T + bias2_z, * gate -----------------
__global__ __launch_bounds__(256, 4) void k_out(const u16* __restrict__ xT,
                                                const u16* __restrict__ wbf,
                                                const float* __restrict__ bias2,
                                                const u16* gateB,
                                                float* outp) {
    __shared__ __align__(16) u16 xl[64 * 128];  // 16KB
    int tid = threadIdx.x, w = tid >> 6, lane = tid & 63;
    int r = lane & 15, kq = lane >> 4;
    long m0 = (long)blockIdx.x * 64;

    // transpose stage: xT[c][m] -> xl[m][c], 4 channels packed per u16x4
    {
        int cg = tid & 31, ms = tid >> 5;
        int c0 = cg * 4;
        const u16* base = xT + m0 + (long)ms * 8;
        bf16x8 v0 = *(const bf16x8*)(base + (long)(c0 + 0) * MM);
        bf16x8 v1 = *(const bf16x8*)(base + (long)(c0 + 1) * MM);
        bf16x8 v2 = *(const bf16x8*)(base + (long)(c0 + 2) * MM);
        bf16x8 v3 = *(const bf16x8*)(base + (long)(c0 + 3) * MM);
        #pragma unroll
        for (int e = 0; e < 8; ++e) {
            int m = ms * 8 + e;
            u16x4 t;
            t.x = (u16)v0[e]; t.y = (u16)v1[e]; t.z = (u16)v2[e]; t.w = (u16)v3[e];
            *(u16x4*)((char*)xl + m * 256 + ((c0 * 2) ^ ((m & 15) << 4))) = t;
        }
    }
    __syncthreads();

    // A-frags + LN stats in registers
    int mlr = w * 16 + r;
    int swm = (mlr & 15) << 4;
    bf16x8 av[4];
    float s = 0.f, s2 = 0.f;
    #pragma unroll
    for (int kb = 0; kb < 4; ++kb) {
        av[kb] = *(const bf16x8*)((const char*)xl + mlr * 256 + ((kb * 64 + kq * 16) ^ swm));
        #pragma unroll
        for (int e = 0; e < 8; ++e) {
            float f = bf2f((u16)av[kb][e]);
            s += f; s2 += f * f;
        }
    }
    s  += __shfl_xor(s, 16);  s  += __shfl_xor(s, 32);
    s2 += __shfl_xor(s2, 16); s2 += __shfl_xor(s2, 32);
    float mu = s * (1.0f / CCH);
    float var = s2 * (1.0f / CCH) - mu * mu;
    float rs = rsqrtf(var + 1e-5f);
    #pragma unroll
    for (int kb = 0; kb < 4; ++kb)
        #pragma unroll
        for (int e = 0; e < 8; ++e) {
            float f = (bf2f((u16)av[kb][e]) - mu) * rs;
            av[kb][e] = (short)f2bf(f);
        }

    // gate preload (gateB aliases outp rows of THIS block only)
    u16 gv[8][4];
    #pragma unroll
    for (int nt = 0; nt < 8; ++nt)
        #pragma unroll
        for (int j = 0; j < 4; ++j) {
            long m = m0 + w * 16 + kq * 4 + j;
            gv[nt][j] = gateB[m * 256 + nt * 16 + r];
        }

    // MFMA vs w_z''
    const u16* Wz = wbf + 5 * 16384;
    f32x4 acc[8];
    #pragma unroll
    for (int nt = 0; nt < 8; ++nt) acc[nt] = {0,0,0,0};
    #pragma unroll
    for (int nt = 0; nt < 8; ++nt) {
        #pragma unroll
        for (int kb = 0; kb < 4; ++kb) {
            bf16x8 bw = *(const bf16x8*)(Wz + (nt * 16 + r) * CCH + kb * 32 + kq * 8);
            acc[nt] = __builtin_amdgcn_mfma_f32_16x16x32_bf16(av[kb], bw, acc[nt], 0, 0, 0);
        }
    }

    __syncthreads();   // ALL gate loads done before any aliasing store

    const float* b2z = bias2 + 5 * CCH;
    #pragma unroll
    for (int nt = 0; nt < 8; ++nt) {
        int cc = nt * 16 + r;
        float bb = b2z[cc];
        #pragma unroll
        for (int j = 0; j < 4; ++j) {
            long m = m0 + w * 16 + kq * 4 + j;
            outp[m * CCH + cc] = (acc[nt][j] + bb) * bf2f(gv[nt][j]);
        }
    }
}

extern "C" void kernel_launch(void* const* d_in, const int* in_sizes, int n_in,
                              void* d_out, int out_size, void* d_ws, size_t ws_size,
                              hipStream_t stream) {
    const float* z       = (const float*)d_in[0];
    const float* mask    = (const float*)d_in[1];
    const float* ln_in_g = (const float*)d_in[2];
    const float* ln_in_b = (const float*)d_in[3];
    const float* w_ag    = (const float*)d_in[4];
    const float* b_ag    = (const float*)d_in[5];
    const float* w_ap    = (const float*)d_in[6];
    const float* b_ap    = (const float*)d_in[7];
    const float* w_bg    = (const float*)d_in[8];
    const float* b_bg    = (const float*)d_in[9];
    const float* w_bp    = (const float*)d_in[10];
    const float* b_bp    = (const float*)d_in[11];
    const float* w_g     = (const float*)d_in[12];
    const float* b_g     = (const float*)d_in[13];
    const float* w_z     = (const float*)d_in[14];
    const float* b_z     = (const float*)d_in[15];
    const float* ln_o_g  = (const float*)d_in[16];
    const float* ln_o_b  = (const float*)d_in[17];
    float* out = (float*)d_out;

    char* ws = (char*)d_ws;
    const size_t SL = (size_t)MM * CCH * 2;  // 64MB per slot
    u16* xT   = (u16*)ws;                     // slot 0 (triangle output)
    u16* aT   = (u16*)(ws + SL);              // slot 1
    u16* bT   = (u16*)(ws + 2 * SL);          // slot 2
    u16* wbf  = (u16*)(ws + 3 * SL);          // 384KB bf16 weights (gamma-folded)
    float* b2 = (float*)(ws + 3 * SL + 6 * 16384 * 2);  // 3KB folded biases
    u16* gateB = (u16*)d_out;                 // gate lives in d_out row heads

    k_prep<<<6, 256, 0, stream>>>(w_ag, w_ap, w_bg, w_bp, w_g, w_z,
                                  b_ag, b_ap, b_bg, b_bp, b_g, b_z,
                                  ln_in_g, ln_in_b, ln_o_g, ln_o_b, wbf, b2);
    k_projLN<<<MM / 64, 256, 0, stream>>>(z, mask, wbf, b2, aT, bT, gateB);
    k_tri<<<2048, 256, 0, stream>>>(aT, bT, xT);
    k_out<<<MM / 64, 256, 0, stream>>>(xT, wbf, b2, gateB, out);
}

// Round 4
// 335.122 us; speedup vs baseline: 1.7122x; 1.7122x over previous
//
#include <hip/hip_runtime.h>

#define NN 512
#define CCH 128
#define MM (NN*NN)   // 262144

using f32x4  = __attribute__((ext_vector_type(4))) float;
using f32x2  = __attribute__((ext_vector_type(2))) float;
using bf16x8 = __attribute__((ext_vector_type(8))) short;
using u16x4  = __attribute__((ext_vector_type(4))) unsigned short;
typedef unsigned short u16;

__device__ __forceinline__ u16 f2bf(float f) {
    unsigned u = __builtin_bit_cast(unsigned, f);
    u += 0x7FFF + ((u >> 16) & 1);
    return (u16)(u >> 16);
}
__device__ __forceinline__ float bf2f(u16 h) {
    unsigned u = ((unsigned)h) << 16;
    return __builtin_bit_cast(float, u);
}
__device__ __forceinline__ float sigm(float x) { return 1.0f / (1.0f + __expf(-x)); }

__device__ __forceinline__ void gl_lds16(const void* g, void* l) {
    __builtin_amdgcn_global_load_lds(
        (const __attribute__((address_space(1))) void*)g,
        (__attribute__((address_space(3))) void*)l, 16, 0, 0);
}

// ---------------- k_prep: fold LN gamma/beta into bf16 weights + biases ----
// Weight rows stored CHUNK-SWIZZLED: logical 16B chunk q of row o lives at
// physical chunk (q ^ (o&7)). Consumers (k_proj LDS reads, k_out global
// reads) apply the same XOR.
__global__ __launch_bounds__(256) void k_prep(
    const float* __restrict__ w0, const float* __restrict__ w1,
    const float* __restrict__ w2, const float* __restrict__ w3,
    const float* __restrict__ w4, const float* __restrict__ w5,
    const float* __restrict__ b0, const float* __restrict__ b1,
    const float* __restrict__ b2, const float* __restrict__ b3,
    const float* __restrict__ b4, const float* __restrict__ b5,
    const float* __restrict__ gin, const float* __restrict__ bin,
    const float* __restrict__ gout, const float* __restrict__ bout,
    u16* __restrict__ wbf, float* __restrict__ bias2) {
    int mat = blockIdx.x;
    const float* W = mat==0?w0:mat==1?w1:mat==2?w2:mat==3?w3:mat==4?w4:w5;
    const float* B = mat==0?b0:mat==1?b1:mat==2?b2:mat==3?b3:mat==4?b4:b5;
    const float* G = (mat==5)? gout : gin;
    const float* Bt= (mat==5)? bout : bin;
    __shared__ float gs[CCH], bs[CCH];
    int tid = threadIdx.x;
    if (tid < CCH) { gs[tid] = G[tid]; bs[tid] = Bt[tid]; }
    __syncthreads();
    int o = tid >> 1, c0 = (tid & 1) * 64;
    const float* src = W + o * CCH + c0;
    char* dstrow = (char*)(wbf + mat * 16384) + o * 256;
    int key = o & 7;
    float dot = 0.f;
    #pragma unroll
    for (int q = 0; q < 16; ++q) {
        f32x4 v = *(const f32x4*)(src + q * 4);
        int c = c0 + q * 4;
        dot += bs[c]*v.x + bs[c+1]*v.y + bs[c+2]*v.z + bs[c+3]*v.w;
        u16x4 p;
        p.x = f2bf(v.x * gs[c]);     p.y = f2bf(v.y * gs[c+1]);
        p.z = f2bf(v.z * gs[c+2]);   p.w = f2bf(v.w * gs[c+3]);
        int chunk = (c0 >> 3) + (q >> 1);
        *(u16x4*)(dstrow + (((chunk ^ key)) << 4) + ((q & 1) << 3)) = p;
    }
    dot += __shfl_xor(dot, 1);
    if ((tid & 1) == 0) bias2[mat * CCH + o] = B[o] + dot;
}

// ---------------- k_ln: LN(z) -> zn (bf16, odd 256B halves of d_out) ------
__global__ __launch_bounds__(256) void k_ln(const float* __restrict__ z,
                                            u16* __restrict__ dz) {
    int tid = threadIdx.x;
    int w = tid >> 6, lane = tid & 63;
    long row = (long)blockIdx.x * 4 + w;
    f32x2 v = *(const f32x2*)(z + row * CCH + lane * 2);
    float s = v.x + v.y, s2 = v.x * v.x + v.y * v.y;
    #pragma unroll
    for (int off = 32; off; off >>= 1) {
        s  += __shfl_xor(s, off);
        s2 += __shfl_xor(s2, off);
    }
    float mu  = s * (1.0f / CCH);
    float var = s2 * (1.0f / CCH) - mu * mu;
    float rs  = rsqrtf(var + 1e-5f);
    float o0 = (v.x - mu) * rs, o1 = (v.y - mu) * rs;
    unsigned pk = (unsigned)f2bf(o0) | ((unsigned)f2bf(o1) << 16);
    *(unsigned*)(dz + row * 256 + 128 + lane * 2) = pk;
}

// ---------------- k_proj: one projection per block -------------------------
// grid (4096 m-blocks, 2 ch-halves, 3 modes). mode 0: a-pair -> aT;
// mode 1: b-pair -> bT; mode 2: gate -> even row-halves of d_out.
__global__ __launch_bounds__(256, 4) void k_proj(
    const u16* dz, const float* __restrict__ mask,
    const u16* __restrict__ wbf, const float* __restrict__ bias2,
    u16* __restrict__ aT, u16* __restrict__ bT) {
    __shared__ __align__(16) u16 w1s[8192];   // 16KB: 64 rows x 256B (swizzled)
    __shared__ __align__(16) u16 w2s[8192];
    int tid = threadIdx.x, w = tid >> 6, lane = tid & 63;
    int r = lane & 15, kq = lane >> 4;
    long m0 = (long)blockIdx.x * 64;
    int ch = blockIdx.y, mode = blockIdx.z;
    int i7 = (int)((m0 >> 9) & 7);
    int mat1 = (mode == 2) ? 4 : mode * 2;

    const char* W1g = (const char*)wbf + (size_t)(mat1 * 16384 + ch * 64 * CCH) * 2;
    const char* W2g = (const char*)wbf + (size_t)((mat1 + 1) * 16384 + ch * 64 * CCH) * 2;
    #pragma unroll
    for (int it = 0; it < 4; ++it) {
        long off = (long)it * 4096 + tid * 16;
        gl_lds16(W1g + off, (char*)w1s + it * 4096 + w * 1024);
        if (mode < 2) gl_lds16(W2g + off, (char*)w2s + it * 4096 + w * 1024);
    }

    // A-fragments from zn (global, bf16)
    bf16x8 av[4];
    long mrow = m0 + w * 16 + r;
    #pragma unroll
    for (int kb = 0; kb < 4; ++kb)
        av[kb] = *(const bf16x8*)(dz + mrow * 256 + 128 + kb * 32 + kq * 8);

    f32x4 mkv = {1.f, 1.f, 1.f, 1.f};
    if (mode < 2) mkv = *(const f32x4*)(mask + m0 + w * 16 + kq * 4);

    __syncthreads();

    f32x4 acc1[4], acc2[4];
    #pragma unroll
    for (int nt = 0; nt < 4; ++nt) { acc1[nt] = {0,0,0,0}; acc2[nt] = {0,0,0,0}; }
    #pragma unroll
    for (int nt = 0; nt < 4; ++nt) {
        int ol = nt * 16 + r;
        int key = ol & 7;
        const char* row1 = (const char*)w1s + ol * 256;
        const char* row2 = (const char*)w2s + ol * 256;
        #pragma unroll
        for (int kb = 0; kb < 4; ++kb) {
            int ph = ((kb * 4 + kq) ^ key) << 4;
            bf16x8 b1 = *(const bf16x8*)(row1 + ph);
            acc1[nt] = __builtin_amdgcn_mfma_f32_16x16x32_bf16(av[kb], b1, acc1[nt], 0, 0, 0);
            if (mode < 2) {
                bf16x8 b2 = *(const bf16x8*)(row2 + ph);
                acc2[nt] = __builtin_amdgcn_mfma_f32_16x16x32_bf16(av[kb], b2, acc2[nt], 0, 0, 0);
            }
        }
    }
    __syncthreads();   // all LDS weight reads done; w1s reusable as tb
    u16* tb = w1s;

    if (mode < 2) {
        int ml0 = w * 16 + kq * 4;
        #pragma unroll
        for (int nt = 0; nt < 4; ++nt) {
            int ccl = nt * 16 + r;
            float b1v = bias2[mat1 * CCH + ch * 64 + ccl];
            float b2v = bias2[(mat1 + 1) * CCH + ch * 64 + ccl];
            u16x4 p;
            #pragma unroll
            for (int j = 0; j < 4; ++j)
                p[j] = f2bf(mkv[j] * sigm(acc1[nt][j] + b1v) * (acc2[nt][j] + b2v));
            *(u16x4*)((char*)tb + ccl * 128 + ((ml0 * 2) ^ ((ccl & 7) << 4))) = p;
        }
        __syncthreads();
        u16* dst = mode ? bT : aT;
        int ccl = tid >> 2, q2 = (tid & 3) * 2;
        const char* srow = (const char*)tb + ccl * 128;
        int key = ccl & 7;
        char* gdst = (char*)(dst + ((long)(ch * 64 + ccl)) * MM) + m0 * 2;
        #pragma unroll
        for (int e = 0; e < 2; ++e) {
            int q = q2 + e;
            bf16x8 v = *(const bf16x8*)(srow + ((q ^ key) << 4));
            *(bf16x8*)(gdst + ((q ^ i7) << 4)) = v;
        }
    } else {
        #pragma unroll
        for (int nt = 0; nt < 4; ++nt) {
            int ccl = nt * 16 + r;
            float b1v = bias2[4 * CCH + ch * 64 + ccl];
            #pragma unroll
            for (int j = 0; j < 4; ++j) {
                int ml = w * 16 + kq * 4 + j;
                *(u16*)((char*)tb + ml * 128 + ((ccl * 2) ^ ((ml & 7) << 4))) =
                    f2bf(sigm(acc1[nt][j] + b1v));
            }
        }
        __syncthreads();
        int ml = tid >> 2, q2 = (tid & 3) * 2;
        const char* srow = (const char*)tb + ml * 128;
        int key = ml & 7;
        char* grow = (char*)(dz + (m0 + ml) * 256 + ch * 64);
        #pragma unroll
        for (int e = 0; e < 2; ++e) {
            int q = q2 + e;
            bf16x8 v = *(const bf16x8*)(srow + ((q ^ key) << 4));
            *(bf16x8*)(grow + q * 16) = v;
        }
    }
}

// ---------------- k_tri: per-channel triangle GEMM, BK=64 ------------------
__global__ __launch_bounds__(256, 4) void k_tri(const u16* __restrict__ aT,
                                                const u16* __restrict__ bT,
                                                u16* __restrict__ xT) {
    __shared__ __align__(16) u16 At[128 * 64];  // 16KB
    __shared__ __align__(16) u16 Bt[128 * 64];
    int tid = threadIdx.x;
    int w = tid >> 6, lane = tid & 63;
    int r = lane & 15, kq = lane >> 4;

    int L = blockIdx.x;
    int xcd = L & 7, idx = L >> 3;
    int c    = xcd + 8 * (idx >> 4);
    int tile = idx & 15;
    int ti = tile >> 2, tj = tile & 3;

    const char* abase = (const char*)(aT + (long)c * MM) + (long)(ti * 128) * 1024;
    const char* bbase = (const char*)(bT + (long)c * MM) + (long)(tj * 128) * 1024;
    int wm = w >> 1, wn = w & 1;

    f32x4 acc[4][4];
    #pragma unroll
    for (int a = 0; a < 4; ++a)
        #pragma unroll
        for (int bq = 0; bq < 4; ++bq) acc[a][bq] = {0.f,0.f,0.f,0.f};

    for (int ks = 0; ks < 8; ++ks) {
        const char* asrc = abase + ks * 128;
        const char* bsrc = bbase + ks * 128;
        #pragma unroll
        for (int it = 0; it < 4; ++it) {
            int u = it * 256 + tid;
            long goff = (long)(u >> 3) * 1024 + (u & 7) * 16;
            gl_lds16(asrc + goff, (char*)At + it * 4096 + w * 1024);
            gl_lds16(bsrc + goff, (char*)Bt + it * 4096 + w * 1024);
        }
        __syncthreads();

        #pragma unroll
        for (int kh = 0; kh < 2; ++kh) {
            bf16x8 af[4];
            #pragma unroll
            for (int mt = 0; mt < 4; ++mt) {
                int rowa = wm * 64 + mt * 16 + r;
                af[mt] = *(const bf16x8*)((const char*)At + rowa * 128 +
                                          (((kh * 4 + kq) ^ (r & 7)) << 4));
            }
            #pragma unroll
            for (int nt = 0; nt < 4; ++nt) {
                int rowb = wn * 64 + nt * 16 + r;
                bf16x8 bf = *(const bf16x8*)((const char*)Bt + rowb * 128 +
                                             (((kh * 4 + kq) ^ (r & 7)) << 4));
                #pragma unroll
                for (int mt = 0; mt < 4; ++mt)
                    acc[mt][nt] = __builtin_amdgcn_mfma_f32_16x16x32_bf16(af[mt], bf, acc[mt][nt], 0, 0, 0);
            }
        }
        __syncthreads();
    }

    u16* xbase = xT + (long)c * MM;
    int gi0 = ti * 128 + wm * 64;
    int gj0 = tj * 128 + wn * 64 + r;
    #pragma unroll
    for (int mt = 0; mt < 4; ++mt)
        #pragma unroll
        for (int nt = 0; nt < 4; ++nt)
            #pragma unroll
            for (int j = 0; j < 4; ++j) {
                long gi = gi0 + mt * 16 + kq * 4 + j;
                xbase[gi * NN + gj0 + nt * 16] = f2bf(acc[mt][nt][j]);
            }
}

// ---------------- k_out: LN(x) @ w_z''^T + bias2_z, * gate -----------------
__global__ __launch_bounds__(256, 4) void k_out(const u16* __restrict__ xT,
                                                const u16* __restrict__ wbf,
                                                const float* __restrict__ bias2,
                                                const u16* gateB,
                                                float* outp) {
    __shared__ __align__(16) u16 xl[64 * 128];  // 16KB
    int tid = threadIdx.x, w = tid >> 6, lane = tid & 63;
    int r = lane & 15, kq = lane >> 4;
    long m0 = (long)blockIdx.x * 64;

    // transpose stage: xT[c][m] -> xl[m][c], 4 channels packed per u16x4
    {
        int cg = tid & 31, ms = tid >> 5;
        int c0 = cg * 4;
        const u16* base = xT + m0 + (long)ms * 8;
        bf16x8 v0 = *(const bf16x8*)(base + (long)(c0 + 0) * MM);
        bf16x8 v1 = *(const bf16x8*)(base + (long)(c0 + 1) * MM);
        bf16x8 v2 = *(const bf16x8*)(base + (long)(c0 + 2) * MM);
        bf16x8 v3 = *(const bf16x8*)(base + (long)(c0 + 3) * MM);
        #pragma unroll
        for (int e = 0; e < 8; ++e) {
            int m = ms * 8 + e;
            u16x4 t;
            t.x = (u16)v0[e]; t.y = (u16)v1[e]; t.z = (u16)v2[e]; t.w = (u16)v3[e];
            *(u16x4*)((char*)xl + m * 256 + ((c0 * 2) ^ ((m & 15) << 4))) = t;
        }
    }
    __syncthreads();

    // A-frags + LN stats in registers
    int mlr = w * 16 + r;
    int swm = (mlr & 15) << 4;
    bf16x8 av[4];
    float s = 0.f, s2 = 0.f;
    #pragma unroll
    for (int kb = 0; kb < 4; ++kb) {
        av[kb] = *(const bf16x8*)((const char*)xl + mlr * 256 + ((kb * 64 + kq * 16) ^ swm));
        #pragma unroll
        for (int e = 0; e < 8; ++e) {
            float f = bf2f((u16)av[kb][e]);
            s += f; s2 += f * f;
        }
    }
    s  += __shfl_xor(s, 16);  s  += __shfl_xor(s, 32);
    s2 += __shfl_xor(s2, 16); s2 += __shfl_xor(s2, 32);
    float mu = s * (1.0f / CCH);
    float var = s2 * (1.0f / CCH) - mu * mu;
    float rs = rsqrtf(var + 1e-5f);
    #pragma unroll
    for (int kb = 0; kb < 4; ++kb)
        #pragma unroll
        for (int e = 0; e < 8; ++e) {
            float f = (bf2f((u16)av[kb][e]) - mu) * rs;
            av[kb][e] = (short)f2bf(f);
        }

    // gate preload (gateB aliases outp rows of THIS block only)
    u16 gv[8][4];
    #pragma unroll
    for (int nt = 0; nt < 8; ++nt)
        #pragma unroll
        for (int j = 0; j < 4; ++j) {
            long m = m0 + w * 16 + kq * 4 + j;
            gv[nt][j] = gateB[m * 256 + nt * 16 + r];
        }

    // MFMA vs w_z'' (global reads, chunk-swizzled layout)
    const char* Wz = (const char*)(wbf + 5 * 16384);
    f32x4 acc[8];
    #pragma unroll
    for (int nt = 0; nt < 8; ++nt) acc[nt] = {0,0,0,0};
    #pragma unroll
    for (int nt = 0; nt < 8; ++nt) {
        int ol = nt * 16 + r;
        int key = ol & 7;
        const char* row = Wz + ol * 256;
        #pragma unroll
        for (int kb = 0; kb < 4; ++kb) {
            bf16x8 bw = *(const bf16x8*)(row + (((kb * 4 + kq) ^ key) << 4));
            acc[nt] = __builtin_amdgcn_mfma_f32_16x16x32_bf16(av[kb], bw, acc[nt], 0, 0, 0);
        }
    }

    __syncthreads();   // ALL gate loads done before any aliasing store

    const float* b2z = bias2 + 5 * CCH;
    #pragma unroll
    for (int nt = 0; nt < 8; ++nt) {
        int cc = nt * 16 + r;
        float bb = b2z[cc];
        #pragma unroll
        for (int j = 0; j < 4; ++j) {
            long m = m0 + w * 16 + kq * 4 + j;
            outp[m * CCH + cc] = (acc[nt][j] + bb) * bf2f(gv[nt][j]);
        }
    }
}

extern "C" void kernel_launch(void* const* d_in, const int* in_sizes, int n_in,
                              void* d_out, int out_size, void* d_ws, size_t ws_size,
                              hipStream_t stream) {
    const float* z       = (const float*)d_in[0];
    const float* mask    = (const float*)d_in[1];
    const float* ln_in_g = (const float*)d_in[2];
    const float* ln_in_b = (const float*)d_in[3];
    const float* w_ag    = (const float*)d_in[4];
    const float* b_ag    = (const float*)d_in[5];
    const float* w_ap    = (const float*)d_in[6];
    const float* b_ap    = (const float*)d_in[7];
    const float* w_bg    = (const float*)d_in[8];
    const float* b_bg    = (const float*)d_in[9];
    const float* w_bp    = (const float*)d_in[10];
    const float* b_bp    = (const float*)d_in[11];
    const float* w_g     = (const float*)d_in[12];
    const float* b_g     = (const float*)d_in[13];
    const float* w_z     = (const float*)d_in[14];
    const float* b_z     = (const float*)d_in[15];
    const float* ln_o_g  = (const float*)d_in[16];
    const float* ln_o_b  = (const float*)d_in[17];
    float* out = (float*)d_out;
    u16* dz = (u16*)d_out;   // row m: gate bf16 at u16[0,128), zn bf16 at u16[128,256)

    char* ws = (char*)d_ws;
    const size_t SL = (size_t)MM * CCH * 2;  // 64MB per slot
    u16* xT   = (u16*)ws;
    u16* aT   = (u16*)(ws + SL);
    u16* bT   = (u16*)(ws + 2 * SL);
    u16* wbf  = (u16*)(ws + 3 * SL);                       // 192KB swizzled bf16 weights
    float* b2 = (float*)(ws + 3 * SL + 6 * 16384 * 2);     // 3KB folded biases

    k_prep<<<6, 256, 0, stream>>>(w_ag, w_ap, w_bg, w_bp, w_g, w_z,
                                  b_ag, b_ap, b_bg, b_bp, b_g, b_z,
                                  ln_in_g, ln_in_b, ln_o_g, ln_o_b, wbf, b2);
    k_ln<<<MM / 4, 256, 0, stream>>>(z, dz);
    k_proj<<<dim3(MM / 64, 2, 3), 256, 0, stream>>>(dz, mask, wbf, b2, aT, bT);
    k_tri<<<2048, 256, 0, stream>>>(aT, bT, xT);
    k_out<<<MM / 64, 256, 0, stream>>>(xT, wbf, b2, dz, out);
}